// Round 1
// baseline (158.831 us; speedup 1.0000x reference)
//
#include <hip/hip_runtime.h>
#include <stdint.h>

// Problem constants
#define BATCH 4096
#define DIN   512
#define NT    64      // trees
#define NL    64      // leaves
#define LD    128     // leaf dims
#define KTOT  4096    // NT*NL

typedef __attribute__((ext_vector_type(8))) short bf16x8;
typedef __attribute__((ext_vector_type(4))) float f32x4;

typedef const __attribute__((address_space(1))) unsigned char* gcp_t;
typedef __attribute__((address_space(3))) unsigned char* lp_t;

__device__ __forceinline__ void gl_lds16(const void* g, void* l) {
  __builtin_amdgcn_global_load_lds((gcp_t)g, (lp_t)l, 16, 0, 0);
}

__device__ __forceinline__ unsigned short f2bf(float f) {
  union { float f; unsigned u; } a; a.f = f;
  unsigned r = a.u + 0x7FFFu + ((a.u >> 16) & 1u);
  return (unsigned short)(r >> 16);
}

// ---------------- prep: x fp32 -> bf16 ----------------
__global__ void prep_x_k(const float* __restrict__ x, unsigned short* __restrict__ xb) {
  int i = blockIdx.x * 256 + threadIdx.x;     // over 4096*512/4 float4s
  float4 v = ((const float4*)x)[i];
  ushort4 o;
  o.x = f2bf(v.x); o.y = f2bf(v.y); o.z = f2bf(v.z); o.w = f2bf(v.w);
  ((ushort4*)xb)[i] = o;
}

// ---------------- prep: W(63,512,64) -> Wt[t][n][d] bf16, n padded to 64 -------
__global__ void prep_wt_k(const float* __restrict__ W, unsigned short* __restrict__ Wt) {
  __shared__ float buf[128 * 64];   // [d_local][t]
  int n = blockIdx.x;               // 0..63 (63 = zero pad row)
  int tid = threadIdx.x;
  for (int d0 = 0; d0 < 512; d0 += 128) {
    if (n < 63) {
      for (int it = 0; it < 32; ++it) {
        int idx = it * 256 + tid;   // idx = i*64 + t
        buf[idx] = W[n * 32768 + (d0 + (idx >> 6)) * 64 + (idx & 63)];
      }
    }
    __syncthreads();
    int t = tid >> 2, q = tid & 3;
    unsigned short vals[32];
    #pragma unroll
    for (int j = 0; j < 32; ++j)
      vals[j] = (n < 63) ? f2bf(buf[(q * 32 + j) * 64 + t]) : (unsigned short)0;
    uint4* dst = (uint4*)(Wt + t * 32768 + n * 512 + d0 + q * 32);
    const uint4* src = (const uint4*)vals;
    dst[0] = src[0]; dst[1] = src[1]; dst[2] = src[2]; dst[3] = src[3];
    __syncthreads();
  }
}

// ------- prep: Wv2[d][kappa] bf16, kappa = t*64+l, w = lw * softmax(gates, t) -------
__global__ void prep_wv_k(const float* __restrict__ gates, const float* __restrict__ lw,
                          unsigned short* __restrict__ Wv2) {
  __shared__ float gb[4096];   // [l*64 + t]
  __shared__ float lb[4096];
  __shared__ float wv[4096];
  int d = blockIdx.x;          // 0..127
  int tid = threadIdx.x;
  for (int it = 0; it < 16; ++it) {
    int idx = it * 256 + tid;  // l*64 + t
    int l = idx >> 6, t = idx & 63;
    int ga = l * 8192 + d * 64 + t;
    gb[idx] = gates[ga];
    lb[idx] = lw[ga];
  }
  __syncthreads();
  int wave = tid >> 6, lane = tid & 63;
  for (int l = wave; l < 64; l += 4) {
    float v = gb[l * 64 + lane];
    float mx = v;
    for (int m = 32; m >= 1; m >>= 1) mx = fmaxf(mx, __shfl_xor(mx, m));
    float e = __expf(v - mx);
    float s = e;
    for (int m = 32; m >= 1; m >>= 1) s += __shfl_xor(s, m);
    wv[l * 64 + lane] = lb[l * 64 + lane] * e / s;
  }
  __syncthreads();
  #pragma unroll
  for (int c = 0; c < 2; ++c) {
    int k0 = tid * 16 + c * 8;
    union { unsigned short u[8]; uint4 v; } o;
    #pragma unroll
    for (int j = 0; j < 8; ++j) {
      int k = k0 + j;                          // kappa = t*64 + l
      o.u[j] = f2bf(wv[(k & 63) * 64 + (k >> 6)]);
    }
    *(uint4*)(Wv2 + (long)d * 4096 + k0) = o.v;
  }
}

// ---------------- GEMM1 fused: logits -> sigmoid -> tree product -> P ----------------
// block: 128 batch rows x 2 trees (128 node-cols). grid (32, 32).
__global__ __launch_bounds__(256, 2) void gemm1_tree_k(
    const unsigned short* __restrict__ xb,   // [4096][512] bf16
    const unsigned short* __restrict__ Wt,   // [64][64][512] bf16
    const float* __restrict__ bias,          // [63][64]
    unsigned short* __restrict__ P)          // [4096][4096] bf16, col = t*64+l
{
  __shared__ unsigned short As[128 * 32];    // [row][k] 64B rows
  __shared__ unsigned short Bs[128 * 32];    // [n'][k]  n' = tree_local*64 + node
  __shared__ _Float16 gbuf[128 * 128];       // [row][n']
  __shared__ float bb[128];

  const int tid = threadIdx.x;
  const int wave = tid >> 6, lane = tid & 63;
  const int b0 = blockIdx.x * 128;
  const int t0 = blockIdx.y * 2;

  if (tid < 128) {
    int n = tid & 63, t = t0 + (tid >> 6);
    bb[tid] = (n < 63) ? bias[n * 64 + t] : 0.0f;
  }

  const f32x4 zero = {0.f, 0.f, 0.f, 0.f};
  f32x4 acc[4][4];
  #pragma unroll
  for (int i = 0; i < 4; ++i)
    #pragma unroll
    for (int j = 0; j < 4; ++j) acc[i][j] = zero;

  const int g0 = wave * 64 + lane;   // granule ids (row = g>>2, chunk = g&3)
  const int g1 = g0 + 256;
  const unsigned short* Ag0 = xb + (long)(b0 + (g0 >> 2)) * 512 + (g0 & 3) * 8;
  const unsigned short* Ag1 = xb + (long)(b0 + (g1 >> 2)) * 512 + (g1 & 3) * 8;
  const unsigned short* Bg0 = Wt + (long)(t0 * 64 + (g0 >> 2)) * 512 + (g0 & 3) * 8;
  const unsigned short* Bg1 = Wt + (long)(t0 * 64 + (g1 >> 2)) * 512 + (g1 & 3) * 8;
  unsigned short* lA0 = As + (wave * 64) * 8;          // wave-uniform LDS bases
  unsigned short* lA1 = As + (wave * 64 + 256) * 8;
  unsigned short* lB0 = Bs + (wave * 64) * 8;
  unsigned short* lB1 = Bs + (wave * 64 + 256) * 8;

  const int wm = (wave >> 1) * 64, wn = (wave & 1) * 64;
  const int mrow = lane & 15, kg = lane >> 4;

  for (int kk = 0; kk < 512; kk += 32) {
    __syncthreads();
    gl_lds16(Ag0 + kk, lA0);
    gl_lds16(Ag1 + kk, lA1);
    gl_lds16(Bg0 + kk, lB0);
    gl_lds16(Bg1 + kk, lB1);
    asm volatile("s_waitcnt vmcnt(0)" ::: "memory");
    __syncthreads();

    bf16x8 fa[4], fb[4];
    #pragma unroll
    for (int i = 0; i < 4; ++i)
      fa[i] = *(const bf16x8*)(As + (wm + i * 16 + mrow) * 32 + kg * 8);
    #pragma unroll
    for (int j = 0; j < 4; ++j)
      fb[j] = *(const bf16x8*)(Bs + (wn + j * 16 + mrow) * 32 + kg * 8);
    #pragma unroll
    for (int i = 0; i < 4; ++i)
      #pragma unroll
      for (int j = 0; j < 4; ++j)
        acc[i][j] = __builtin_amdgcn_mfma_f32_16x16x32_bf16(fa[i], fb[j], acc[i][j], 0, 0, 0);
  }

  // epilogue 1: bias + sigmoid -> gbuf
  #pragma unroll
  for (int i = 0; i < 4; ++i)
    #pragma unroll
    for (int j = 0; j < 4; ++j) {
      int col = wn + j * 16 + mrow;
      float bv = bb[col];
      #pragma unroll
      for (int r = 0; r < 4; ++r) {
        int row = wm + i * 16 + kg * 4 + r;
        float z = acc[i][j][r] + bv;
        gbuf[row * 128 + col] = (_Float16)(1.0f / (1.0f + __expf(-z)));
      }
    }
  __syncthreads();

  // epilogue 2: soft-tree path product -> P (bf16)
  // leaf l: level lev uses node (2^lev-1) + (l >> (6-lev)); branch bit (l >> (5-lev)) & 1
  #pragma unroll
  for (int cc = 0; cc < 8; ++cc) {
    int chunk = cc * 256 + tid;        // 2048 chunks = 128 rows * 2 trees * 8 octets
    int row = chunk >> 4;
    int tr  = (chunk >> 3) & 1;
    int oct = chunk & 7;
    const _Float16* grow = gbuf + row * 128 + tr * 64;
    int l0 = oct * 8;
    float pre = 1.0f;
    #pragma unroll
    for (int lev = 0; lev < 3; ++lev) {
      int node = (1 << lev) - 1 + (l0 >> (6 - lev));
      float g = (float)grow[node];
      pre *= ((l0 >> (5 - lev)) & 1) ? (1.0f - g) : g;
    }
    union { unsigned short u[8]; uint4 v; } ou;
    #pragma unroll
    for (int j = 0; j < 8; ++j) {
      int l = l0 + j;
      float p = pre;
      #pragma unroll
      for (int lev = 3; lev < 6; ++lev) {
        int node = (1 << lev) - 1 + (l >> (6 - lev));
        float g = (float)grow[node];
        p *= ((l >> (5 - lev)) & 1) ? (1.0f - g) : g;
      }
      ou.u[j] = f2bf(p);
    }
    *(uint4*)(P + (long)(b0 + row) * 4096 + (t0 + tr) * 64 + l0) = ou.v;
  }
}

// ---------------- GEMM2: out = P(4096x4096) * Wv2^T, split-K by 8 ----------------
__global__ __launch_bounds__(256, 2) void gemm2_k(
    const unsigned short* __restrict__ P,    // [4096][4096] bf16
    const unsigned short* __restrict__ Wv2,  // [128][4096] bf16
    float* __restrict__ part)                // [8][4096][128]
{
  __shared__ unsigned short As[128 * 32];
  __shared__ unsigned short Bs[128 * 32];
  const int tid = threadIdx.x;
  const int wave = tid >> 6, lane = tid & 63;
  const int b0 = blockIdx.x * 128;
  const int kc = blockIdx.y;                 // K chunk of 512

  const f32x4 zero = {0.f, 0.f, 0.f, 0.f};
  f32x4 acc[4][4];
  #pragma unroll
  for (int i = 0; i < 4; ++i)
    #pragma unroll
    for (int j = 0; j < 4; ++j) acc[i][j] = zero;

  const int g0 = wave * 64 + lane;
  const int g1 = g0 + 256;
  const unsigned short* Ag0 = P + (long)(b0 + (g0 >> 2)) * 4096 + kc * 512 + (g0 & 3) * 8;
  const unsigned short* Ag1 = P + (long)(b0 + (g1 >> 2)) * 4096 + kc * 512 + (g1 & 3) * 8;
  const unsigned short* Bg0 = Wv2 + (long)(g0 >> 2) * 4096 + kc * 512 + (g0 & 3) * 8;
  const unsigned short* Bg1 = Wv2 + (long)(g1 >> 2) * 4096 + kc * 512 + (g1 & 3) * 8;
  unsigned short* lA0 = As + (wave * 64) * 8;
  unsigned short* lA1 = As + (wave * 64 + 256) * 8;
  unsigned short* lB0 = Bs + (wave * 64) * 8;
  unsigned short* lB1 = Bs + (wave * 64 + 256) * 8;

  const int wm = (wave >> 1) * 64, wn = (wave & 1) * 64;
  const int mrow = lane & 15, kg = lane >> 4;

  for (int kk = 0; kk < 512; kk += 32) {
    __syncthreads();
    gl_lds16(Ag0 + kk, lA0);
    gl_lds16(Ag1 + kk, lA1);
    gl_lds16(Bg0 + kk, lB0);
    gl_lds16(Bg1 + kk, lB1);
    asm volatile("s_waitcnt vmcnt(0)" ::: "memory");
    __syncthreads();

    bf16x8 fa[4], fb[4];
    #pragma unroll
    for (int i = 0; i < 4; ++i)
      fa[i] = *(const bf16x8*)(As + (wm + i * 16 + mrow) * 32 + kg * 8);
    #pragma unroll
    for (int j = 0; j < 4; ++j)
      fb[j] = *(const bf16x8*)(Bs + (wn + j * 16 + mrow) * 32 + kg * 8);
    #pragma unroll
    for (int i = 0; i < 4; ++i)
      #pragma unroll
      for (int j = 0; j < 4; ++j)
        acc[i][j] = __builtin_amdgcn_mfma_f32_16x16x32_bf16(fa[i], fb[j], acc[i][j], 0, 0, 0);
  }

  float* dst = part + (long)kc * (4096 * 128);
  #pragma unroll
  for (int i = 0; i < 4; ++i)
    #pragma unroll
    for (int j = 0; j < 4; ++j) {
      int col = wn + j * 16 + mrow;
      #pragma unroll
      for (int r = 0; r < 4; ++r) {
        int row = wm + i * 16 + kg * 4 + r;
        dst[(long)(b0 + row) * 128 + col] = acc[i][j][r];
      }
    }
}

// ---------------- reduce 8 partials -> out ----------------
__global__ void reduce8_k(const float* __restrict__ part, float* __restrict__ out) {
  int i = blockIdx.x * 256 + threadIdx.x;   // over 524288/4 float4s
  float4 s = ((const float4*)part)[i];
  #pragma unroll
  for (int k = 1; k < 8; ++k) {
    float4 v = ((const float4*)part)[k * 131072 + i];
    s.x += v.x; s.y += v.y; s.z += v.z; s.w += v.w;
  }
  ((float4*)out)[i] = s;
}

extern "C" void kernel_launch(void* const* d_in, const int* in_sizes, int n_in,
                              void* d_out, int out_size, void* d_ws, size_t ws_size,
                              hipStream_t stream) {
  const float* x     = (const float*)d_in[0];
  const float* W     = (const float*)d_in[1];
  const float* b     = (const float*)d_in[2];
  const float* lw    = (const float*)d_in[3];
  const float* gates = (const float*)d_in[4];
  float* out = (float*)d_out;

  char* ws = (char*)d_ws;
  unsigned short* xb  = (unsigned short*)(ws);                    // 4 MB
  unsigned short* Wt  = (unsigned short*)(ws + (4l  << 20));      // 4 MB
  unsigned short* Wv2 = (unsigned short*)(ws + (8l  << 20));      // 1 MB
  unsigned short* P   = (unsigned short*)(ws + (16l << 20));      // 32 MB
  float*          prt = (float*)(ws + (48l << 20));               // 16 MB

  hipLaunchKernelGGL(prep_x_k,     dim3(2048),   dim3(256), 0, stream, x, xb);
  hipLaunchKernelGGL(prep_wt_k,    dim3(64),     dim3(256), 0, stream, W, Wt);
  hipLaunchKernelGGL(prep_wv_k,    dim3(128),    dim3(256), 0, stream, gates, lw, Wv2);
  hipLaunchKernelGGL(gemm1_tree_k, dim3(32, 32), dim3(256), 0, stream, xb, Wt, b, P);
  hipLaunchKernelGGL(gemm2_k,      dim3(32, 8),  dim3(256), 0, stream, P, Wv2, prt);
  hipLaunchKernelGGL(reduce8_k,    dim3(512),    dim3(256), 0, stream, prt, out);
}

// Round 2
// 148.483 us; speedup vs baseline: 1.0697x; 1.0697x over previous
//
#include <hip/hip_runtime.h>
#include <stdint.h>

// Problem constants
#define BATCH 4096
#define DIN   512
#define NT    64      // trees
#define NL    64      // leaves
#define LD    128     // leaf dims

typedef __attribute__((ext_vector_type(8))) short bf16x8;
typedef __attribute__((ext_vector_type(4))) float f32x4;

typedef const __attribute__((address_space(1))) unsigned char* gcp_t;
typedef __attribute__((address_space(3))) unsigned char* lp_t;

__device__ __forceinline__ void gl_lds16(const void* g, void* l) {
  __builtin_amdgcn_global_load_lds((gcp_t)g, (lp_t)l, 16, 0, 0);
}

__device__ __forceinline__ unsigned short f2bf(float f) {
  union { float f; unsigned u; } a; a.f = f;
  unsigned r = a.u + 0x7FFFu + ((a.u >> 16) & 1u);
  return (unsigned short)(r >> 16);
}

// ---------------- merged prep kernel ----------------
// blocks [0,2048): x fp32 -> bf16
// blocks [2048,2304): W(63,512,64) -> Wt[t][n][d] bf16 (n padded to 64); 4 d-chunks per n
// blocks [2304,2432): w = lw * softmax(gates, t) -> Wv2[d][kappa] bf16, kappa = t*64+l
__global__ __launch_bounds__(256) void prep_all_k(
    const float* __restrict__ x, const float* __restrict__ W,
    const float* __restrict__ gates, const float* __restrict__ lw,
    unsigned short* __restrict__ xb, unsigned short* __restrict__ Wt,
    unsigned short* __restrict__ Wv2) {
  __shared__ float smem[12288];   // 48 KB
  const int bx = blockIdx.x;
  const int tid = threadIdx.x;

  if (bx < 2048) {
    // ---- prep x ----
    int i = bx * 256 + tid;
    float4 v = ((const float4*)x)[i];
    ushort4 o;
    o.x = f2bf(v.x); o.y = f2bf(v.y); o.z = f2bf(v.z); o.w = f2bf(v.w);
    ((ushort4*)xb)[i] = o;
  } else if (bx < 2304) {
    // ---- prep Wt ----
    int bb = bx - 2048;
    int n = bb >> 2, d0 = (bb & 3) * 128;
    float* buf = smem;   // [d_local][t], 128*64 floats = 32 KB
    if (n < 63) {
      for (int it = 0; it < 32; ++it) {
        int idx = it * 256 + tid;   // idx = d_local*64 + t
        buf[idx] = W[n * 32768 + (d0 + (idx >> 6)) * 64 + (idx & 63)];
      }
    }
    __syncthreads();
    int t = tid >> 2, q = tid & 3;
    unsigned short vals[32];
    #pragma unroll
    for (int j = 0; j < 32; ++j)
      vals[j] = (n < 63) ? f2bf(buf[(q * 32 + j) * 64 + t]) : (unsigned short)0;
    uint4* dst = (uint4*)(Wt + t * 32768 + n * 512 + d0 + q * 32);
    const uint4* src = (const uint4*)vals;
    dst[0] = src[0]; dst[1] = src[1]; dst[2] = src[2]; dst[3] = src[3];
  } else {
    // ---- prep Wv2 ----
    int d = bx - 2304;           // 0..127
    float* gb = smem;            // [l*64 + t]
    float* lb = smem + 4096;
    float* wv = smem + 8192;
    for (int it = 0; it < 16; ++it) {
      int idx = it * 256 + tid;  // l*64 + t
      int l = idx >> 6;
      int ga = l * 8192 + d * 64 + (idx & 63);
      gb[idx] = gates[ga];
      lb[idx] = lw[ga];
    }
    __syncthreads();
    int wave = tid >> 6, lane = tid & 63;
    for (int l = wave; l < 64; l += 4) {
      float v = gb[l * 64 + lane];
      float mx = v;
      for (int m = 32; m >= 1; m >>= 1) mx = fmaxf(mx, __shfl_xor(mx, m));
      float e = __expf(v - mx);
      float s = e;
      for (int m = 32; m >= 1; m >>= 1) s += __shfl_xor(s, m);
      wv[l * 64 + lane] = lb[l * 64 + lane] * e / s;
    }
    __syncthreads();
    #pragma unroll
    for (int c = 0; c < 2; ++c) {
      int k0 = tid * 16 + c * 8;
      union { unsigned short u[8]; uint4 v; } o;
      #pragma unroll
      for (int j = 0; j < 8; ++j) {
        int k = k0 + j;                          // kappa = t*64 + l
        o.u[j] = f2bf(wv[(k & 63) * 64 + (k >> 6)]);
      }
      *(uint4*)(Wv2 + (long)d * 4096 + k0) = o.v;
    }
  }
}

// ---------------- GEMM1 fused: logits -> sigmoid -> tree product -> P ----------------
// block: 128 batch rows x 2 trees (128 node-cols). grid (32, 32).
// LDS 48.5 KB -> 3 blocks/CU; __launch_bounds__(256,3) caps VGPR at ~170 to fit.
__global__ __launch_bounds__(256, 3) void gemm1_tree_k(
    const unsigned short* __restrict__ xb,   // [4096][512] bf16
    const unsigned short* __restrict__ Wt,   // [64][64][512] bf16
    const float* __restrict__ bias,          // [63][64]
    unsigned short* __restrict__ P)          // [4096][4096] bf16, col = t*64+l
{
  __shared__ unsigned short As[128 * 32];    // [row][k] 64B rows
  __shared__ unsigned short Bs[128 * 32];    // [n'][k]  n' = tree_local*64 + node
  __shared__ _Float16 gbuf[128 * 128];       // [row][n']
  __shared__ float bb[128];

  const int tid = threadIdx.x;
  const int wave = tid >> 6, lane = tid & 63;
  const int b0 = blockIdx.x * 128;
  const int t0 = blockIdx.y * 2;

  if (tid < 128) {
    int n = tid & 63, t = t0 + (tid >> 6);
    bb[tid] = (n < 63) ? bias[n * 64 + t] : 0.0f;
  }

  const f32x4 zero = {0.f, 0.f, 0.f, 0.f};
  f32x4 acc[4][4];
  #pragma unroll
  for (int i = 0; i < 4; ++i)
    #pragma unroll
    for (int j = 0; j < 4; ++j) acc[i][j] = zero;

  const int g0 = wave * 64 + lane;   // granule ids (row = g>>2, chunk = g&3)
  const int g1 = g0 + 256;
  const unsigned short* Ag0 = xb + (long)(b0 + (g0 >> 2)) * 512 + (g0 & 3) * 8;
  const unsigned short* Ag1 = xb + (long)(b0 + (g1 >> 2)) * 512 + (g1 & 3) * 8;
  const unsigned short* Bg0 = Wt + (long)(t0 * 64 + (g0 >> 2)) * 512 + (g0 & 3) * 8;
  const unsigned short* Bg1 = Wt + (long)(t0 * 64 + (g1 >> 2)) * 512 + (g1 & 3) * 8;
  unsigned short* lA0 = As + (wave * 64) * 8;          // wave-uniform LDS bases
  unsigned short* lA1 = As + (wave * 64 + 256) * 8;
  unsigned short* lB0 = Bs + (wave * 64) * 8;
  unsigned short* lB1 = Bs + (wave * 64 + 256) * 8;

  const int wm = (wave >> 1) * 64, wn = (wave & 1) * 64;
  const int mrow = lane & 15, kg = lane >> 4;

  for (int kk = 0; kk < 512; kk += 32) {
    __syncthreads();
    gl_lds16(Ag0 + kk, lA0);
    gl_lds16(Ag1 + kk, lA1);
    gl_lds16(Bg0 + kk, lB0);
    gl_lds16(Bg1 + kk, lB1);
    asm volatile("s_waitcnt vmcnt(0)" ::: "memory");
    __syncthreads();

    bf16x8 fa[4], fb[4];
    #pragma unroll
    for (int i = 0; i < 4; ++i)
      fa[i] = *(const bf16x8*)(As + (wm + i * 16 + mrow) * 32 + kg * 8);
    #pragma unroll
    for (int j = 0; j < 4; ++j)
      fb[j] = *(const bf16x8*)(Bs + (wn + j * 16 + mrow) * 32 + kg * 8);
    #pragma unroll
    for (int i = 0; i < 4; ++i)
      #pragma unroll
      for (int j = 0; j < 4; ++j)
        acc[i][j] = __builtin_amdgcn_mfma_f32_16x16x32_bf16(fa[i], fb[j], acc[i][j], 0, 0, 0);
  }

  // epilogue 1: bias + sigmoid -> gbuf
  #pragma unroll
  for (int i = 0; i < 4; ++i)
    #pragma unroll
    for (int j = 0; j < 4; ++j) {
      int col = wn + j * 16 + mrow;
      float bv = bb[col];
      #pragma unroll
      for (int r = 0; r < 4; ++r) {
        int row = wm + i * 16 + kg * 4 + r;
        float z = acc[i][j][r] + bv;
        gbuf[row * 128 + col] = (_Float16)(1.0f / (1.0f + __expf(-z)));
      }
    }
  __syncthreads();

  // epilogue 2: soft-tree path product -> P (bf16)
  // leaf l: level lev uses node (2^lev-1) + (l >> (6-lev)); branch bit (l >> (5-lev)) & 1
  #pragma unroll
  for (int cc = 0; cc < 8; ++cc) {
    int chunk = cc * 256 + tid;        // 2048 chunks = 128 rows * 2 trees * 8 octets
    int row = chunk >> 4;
    int tr  = (chunk >> 3) & 1;
    int oct = chunk & 7;
    const _Float16* grow = gbuf + row * 128 + tr * 64;
    int l0 = oct * 8;
    float pre = 1.0f;
    #pragma unroll
    for (int lev = 0; lev < 3; ++lev) {
      int node = (1 << lev) - 1 + (l0 >> (6 - lev));
      float g = (float)grow[node];
      pre *= ((l0 >> (5 - lev)) & 1) ? (1.0f - g) : g;
    }
    union { unsigned short u[8]; uint4 v; } ou;
    #pragma unroll
    for (int j = 0; j < 8; ++j) {
      int l = l0 + j;
      float p = pre;
      #pragma unroll
      for (int lev = 3; lev < 6; ++lev) {
        int node = (1 << lev) - 1 + (l >> (6 - lev));
        float g = (float)grow[node];
        p *= ((l >> (5 - lev)) & 1) ? (1.0f - g) : g;
      }
      ou.u[j] = f2bf(p);
    }
    *(uint4*)(P + (long)(b0 + row) * 4096 + (t0 + tr) * 64 + l0) = ou.v;
  }
}

// ---------------- GEMM2: out += P(4096x4096) * Wv2^T, split-K by 8, atomic accumulate ----
__global__ __launch_bounds__(256, 2) void gemm2_k(
    const unsigned short* __restrict__ P,    // [4096][4096] bf16
    const unsigned short* __restrict__ Wv2,  // [128][4096] bf16
    float* __restrict__ out)                 // [4096][128], pre-zeroed
{
  __shared__ unsigned short As[128 * 32];
  __shared__ unsigned short Bs[128 * 32];
  const int tid = threadIdx.x;
  const int wave = tid >> 6, lane = tid & 63;
  const int b0 = blockIdx.x * 128;
  const int kc = blockIdx.y;                 // K chunk of 512

  const f32x4 zero = {0.f, 0.f, 0.f, 0.f};
  f32x4 acc[4][4];
  #pragma unroll
  for (int i = 0; i < 4; ++i)
    #pragma unroll
    for (int j = 0; j < 4; ++j) acc[i][j] = zero;

  const int g0 = wave * 64 + lane;
  const int g1 = g0 + 256;
  const unsigned short* Ag0 = P + (long)(b0 + (g0 >> 2)) * 4096 + kc * 512 + (g0 & 3) * 8;
  const unsigned short* Ag1 = P + (long)(b0 + (g1 >> 2)) * 4096 + kc * 512 + (g1 & 3) * 8;
  const unsigned short* Bg0 = Wv2 + (long)(g0 >> 2) * 4096 + kc * 512 + (g0 & 3) * 8;
  const unsigned short* Bg1 = Wv2 + (long)(g1 >> 2) * 4096 + kc * 512 + (g1 & 3) * 8;
  unsigned short* lA0 = As + (wave * 64) * 8;
  unsigned short* lA1 = As + (wave * 64 + 256) * 8;
  unsigned short* lB0 = Bs + (wave * 64) * 8;
  unsigned short* lB1 = Bs + (wave * 64 + 256) * 8;

  const int wm = (wave >> 1) * 64, wn = (wave & 1) * 64;
  const int mrow = lane & 15, kg = lane >> 4;

  for (int kk = 0; kk < 512; kk += 32) {
    __syncthreads();
    gl_lds16(Ag0 + kk, lA0);
    gl_lds16(Ag1 + kk, lA1);
    gl_lds16(Bg0 + kk, lB0);
    gl_lds16(Bg1 + kk, lB1);
    asm volatile("s_waitcnt vmcnt(0)" ::: "memory");
    __syncthreads();

    bf16x8 fa[4], fb[4];
    #pragma unroll
    for (int i = 0; i < 4; ++i)
      fa[i] = *(const bf16x8*)(As + (wm + i * 16 + mrow) * 32 + kg * 8);
    #pragma unroll
    for (int j = 0; j < 4; ++j)
      fb[j] = *(const bf16x8*)(Bs + (wn + j * 16 + mrow) * 32 + kg * 8);
    #pragma unroll
    for (int i = 0; i < 4; ++i)
      #pragma unroll
      for (int j = 0; j < 4; ++j)
        acc[i][j] = __builtin_amdgcn_mfma_f32_16x16x32_bf16(fa[i], fb[j], acc[i][j], 0, 0, 0);
  }

  #pragma unroll
  for (int i = 0; i < 4; ++i)
    #pragma unroll
    for (int j = 0; j < 4; ++j) {
      int col = wn + j * 16 + mrow;
      #pragma unroll
      for (int r = 0; r < 4; ++r) {
        int row = wm + i * 16 + kg * 4 + r;
        atomicAdd(&out[(long)(b0 + row) * 128 + col], acc[i][j][r]);
      }
    }
}

extern "C" void kernel_launch(void* const* d_in, const int* in_sizes, int n_in,
                              void* d_out, int out_size, void* d_ws, size_t ws_size,
                              hipStream_t stream) {
  const float* x     = (const float*)d_in[0];
  const float* W     = (const float*)d_in[1];
  const float* b     = (const float*)d_in[2];
  const float* lw    = (const float*)d_in[3];
  const float* gates = (const float*)d_in[4];
  float* out = (float*)d_out;

  char* ws = (char*)d_ws;
  unsigned short* xb  = (unsigned short*)(ws);                    // 4 MB
  unsigned short* Wt  = (unsigned short*)(ws + (4l  << 20));      // 4 MB
  unsigned short* Wv2 = (unsigned short*)(ws + (8l  << 20));      // 1 MB
  unsigned short* P   = (unsigned short*)(ws + (16l << 20));      // 32 MB

  hipMemsetAsync(out, 0, (size_t)4096 * 128 * sizeof(float), stream);
  hipLaunchKernelGGL(prep_all_k,   dim3(2432),   dim3(256), 0, stream,
                     x, W, gates, lw, xb, Wt, Wv2);
  hipLaunchKernelGGL(gemm1_tree_k, dim3(32, 32), dim3(256), 0, stream, xb, Wt, b, P);
  hipLaunchKernelGGL(gemm2_k,      dim3(32, 8),  dim3(256), 0, stream, P, Wv2, out);
}

// Round 3
// 147.838 us; speedup vs baseline: 1.0744x; 1.0044x over previous
//
#include <hip/hip_runtime.h>
#include <stdint.h>

// Problem constants
#define BATCH 4096
#define DIN   512
#define NT    64      // trees
#define NL    64      // leaves
#define LD    128     // leaf dims

typedef __attribute__((ext_vector_type(8))) short bf16x8;
typedef __attribute__((ext_vector_type(8))) _Float16 f16x8;
typedef __attribute__((ext_vector_type(4))) float f32x4;

typedef const __attribute__((address_space(1))) unsigned char* gcp_t;
typedef __attribute__((address_space(3))) unsigned char* lp_t;

__device__ __forceinline__ void gl_lds16(const void* g, void* l) {
  __builtin_amdgcn_global_load_lds((gcp_t)g, (lp_t)l, 16, 0, 0);
}

__device__ __forceinline__ unsigned short f2bf(float f) {
  union { float f; unsigned u; } a; a.f = f;
  unsigned r = a.u + 0x7FFFu + ((a.u >> 16) & 1u);
  return (unsigned short)(r >> 16);
}

// ---------------- merged prep kernel ----------------
// blocks [0,2048): x fp32 -> bf16
// blocks [2048,2304): W(63,512,64) -> Wt[t][n][d] bf16 (n padded to 64); 4 d-chunks per n
// blocks [2304,2432): w = lw * softmax(gates, t) -> Wv2[d][kappa] bf16, kappa = t*64+l
__global__ __launch_bounds__(256) void prep_all_k(
    const float* __restrict__ x, const float* __restrict__ W,
    const float* __restrict__ gates, const float* __restrict__ lw,
    unsigned short* __restrict__ xb, unsigned short* __restrict__ Wt,
    unsigned short* __restrict__ Wv2) {
  __shared__ float smem[12288];   // 48 KB
  const int bx = blockIdx.x;
  const int tid = threadIdx.x;

  if (bx < 2048) {
    // ---- prep x ----
    int i = bx * 256 + tid;
    float4 v = ((const float4*)x)[i];
    ushort4 o;
    o.x = f2bf(v.x); o.y = f2bf(v.y); o.z = f2bf(v.z); o.w = f2bf(v.w);
    ((ushort4*)xb)[i] = o;
  } else if (bx < 2304) {
    // ---- prep Wt ----
    int bb = bx - 2048;
    int n = bb >> 2, d0 = (bb & 3) * 128;
    float* buf = smem;   // [d_local][t], 128*64 floats = 32 KB
    if (n < 63) {
      for (int it = 0; it < 32; ++it) {
        int idx = it * 256 + tid;   // idx = d_local*64 + t
        buf[idx] = W[n * 32768 + (d0 + (idx >> 6)) * 64 + (idx & 63)];
      }
    }
    __syncthreads();
    int t = tid >> 2, q = tid & 3;
    unsigned short vals[32];
    #pragma unroll
    for (int j = 0; j < 32; ++j)
      vals[j] = (n < 63) ? f2bf(buf[(q * 32 + j) * 64 + t]) : (unsigned short)0;
    uint4* dst = (uint4*)(Wt + t * 32768 + n * 512 + d0 + q * 32);
    const uint4* src = (const uint4*)vals;
    dst[0] = src[0]; dst[1] = src[1]; dst[2] = src[2]; dst[3] = src[3];
  } else {
    // ---- prep Wv2 ----
    int d = bx - 2304;           // 0..127
    float* gb = smem;            // [l*64 + t]
    float* lb = smem + 4096;
    float* wv = smem + 8192;
    for (int it = 0; it < 16; ++it) {
      int idx = it * 256 + tid;  // l*64 + t
      int l = idx >> 6;
      int ga = l * 8192 + d * 64 + (idx & 63);
      gb[idx] = gates[ga];
      lb[idx] = lw[ga];
    }
    __syncthreads();
    int wave = tid >> 6, lane = tid & 63;
    for (int l = wave; l < 64; l += 4) {
      float v = gb[l * 64 + lane];
      float mx = v;
      for (int m = 32; m >= 1; m >>= 1) mx = fmaxf(mx, __shfl_xor(mx, m));
      float e = __expf(v - mx);
      float s = e;
      for (int m = 32; m >= 1; m >>= 1) s += __shfl_xor(s, m);
      wv[l * 64 + lane] = lb[l * 64 + lane] * e / s;
    }
    __syncthreads();
    #pragma unroll
    for (int c = 0; c < 2; ++c) {
      int k0 = tid * 16 + c * 8;
      union { unsigned short u[8]; uint4 v; } o;
      #pragma unroll
      for (int j = 0; j < 8; ++j) {
        int k = k0 + j;                          // kappa = t*64 + l
        o.u[j] = f2bf(wv[(k & 63) * 64 + (k >> 6)]);
      }
      *(uint4*)(Wv2 + (long)d * 4096 + k0) = o.v;
    }
  }
}

// ---------------- GEMM1 fused: logits -> sigmoid -> tree product -> P ----------------
// block: 128 batch rows x 2 trees (128 node-cols). grid (32, 32).
// LDS 50.5 KB -> 3 blocks/CU.
__global__ __launch_bounds__(256, 3) void gemm1_tree_k(
    const unsigned short* __restrict__ xb,   // [4096][512] bf16
    const unsigned short* __restrict__ Wt,   // [64][64][512] bf16
    const float* __restrict__ bias,          // [63][64]
    unsigned short* __restrict__ P)          // [4096][4096] bf16, col = t*64+l
{
  __shared__ unsigned short As[128 * 32];    // [row][k] 64B rows
  __shared__ unsigned short Bs[128 * 32];    // [n'][k]  n' = tree_local*64 + node
  __shared__ __align__(16) _Float16 gbuf[128 * 136];  // [row][n'], stride 136 (16B-aligned rows, 8-way-floor b128 reads)
  __shared__ float bb[128];

  const int tid = threadIdx.x;
  const int wave = tid >> 6, lane = tid & 63;
  const int b0 = blockIdx.x * 128;
  const int t0 = blockIdx.y * 2;

  if (tid < 128) {
    int n = tid & 63, t = t0 + (tid >> 6);
    bb[tid] = (n < 63) ? bias[n * 64 + t] : 0.0f;
  }

  const f32x4 zero = {0.f, 0.f, 0.f, 0.f};
  f32x4 acc[4][4];
  #pragma unroll
  for (int i = 0; i < 4; ++i)
    #pragma unroll
    for (int j = 0; j < 4; ++j) acc[i][j] = zero;

  const int g0 = wave * 64 + lane;   // granule ids (row = g>>2, chunk = g&3)
  const int g1 = g0 + 256;
  const unsigned short* Ag0 = xb + (long)(b0 + (g0 >> 2)) * 512 + (g0 & 3) * 8;
  const unsigned short* Ag1 = xb + (long)(b0 + (g1 >> 2)) * 512 + (g1 & 3) * 8;
  const unsigned short* Bg0 = Wt + (long)(t0 * 64 + (g0 >> 2)) * 512 + (g0 & 3) * 8;
  const unsigned short* Bg1 = Wt + (long)(t0 * 64 + (g1 >> 2)) * 512 + (g1 & 3) * 8;
  unsigned short* lA0 = As + (wave * 64) * 8;          // wave-uniform LDS bases
  unsigned short* lA1 = As + (wave * 64 + 256) * 8;
  unsigned short* lB0 = Bs + (wave * 64) * 8;
  unsigned short* lB1 = Bs + (wave * 64 + 256) * 8;

  const int wm = (wave >> 1) * 64, wn = (wave & 1) * 64;
  const int mrow = lane & 15, kg = lane >> 4;

  for (int kk = 0; kk < 512; kk += 32) {
    __syncthreads();
    gl_lds16(Ag0 + kk, lA0);
    gl_lds16(Ag1 + kk, lA1);
    gl_lds16(Bg0 + kk, lB0);
    gl_lds16(Bg1 + kk, lB1);
    asm volatile("s_waitcnt vmcnt(0)" ::: "memory");
    __syncthreads();

    bf16x8 fa[4], fb[4];
    #pragma unroll
    for (int i = 0; i < 4; ++i)
      fa[i] = *(const bf16x8*)(As + (wm + i * 16 + mrow) * 32 + kg * 8);
    #pragma unroll
    for (int j = 0; j < 4; ++j)
      fb[j] = *(const bf16x8*)(Bs + (wn + j * 16 + mrow) * 32 + kg * 8);
    #pragma unroll
    for (int i = 0; i < 4; ++i)
      #pragma unroll
      for (int j = 0; j < 4; ++j)
        acc[i][j] = __builtin_amdgcn_mfma_f32_16x16x32_bf16(fa[i], fb[j], acc[i][j], 0, 0, 0);
  }

  // epilogue 1: bias + sigmoid -> gbuf (f16, row stride 136)
  #pragma unroll
  for (int i = 0; i < 4; ++i)
    #pragma unroll
    for (int j = 0; j < 4; ++j) {
      int col = wn + j * 16 + mrow;
      float bv = bb[col];
      #pragma unroll
      for (int r = 0; r < 4; ++r) {
        int row = wm + i * 16 + kg * 4 + r;
        float z = acc[i][j][r] + bv;
        gbuf[row * 136 + col] = (_Float16)(1.0f / (1.0f + __expf(-z)));
      }
    }
  __syncthreads();

  // epilogue 2: one thread per (row, tree) — vector g-row load + register DFS.
  // leaf l: level lev uses node (2^lev-1) + (l >> (6-lev)); branch bit (l >> (5-lev)) & 1
  {
    const int row = tid >> 1, tr = tid & 1;
    const _Float16* grow = gbuf + row * 136 + tr * 64;
    float g[63];
    #pragma unroll
    for (int c = 0; c < 8; ++c) {
      f16x8 gv = *(const f16x8*)(grow + c * 8);
      #pragma unroll
      for (int j = 0; j < 8; ++j) {
        int n = c * 8 + j;
        if (n < 63) g[n] = (float)gv[j];
      }
    }
    // prefix products to depth 3 (octet o = l>>3, bits b5b4b3)
    float P3[8];
    {
      float a0 = g[0],            a1 = 1.0f - g[0];          // lev0: node 0
      float c0 = a0 * g[1],       c1 = a0 * (1.0f - g[1]);   // lev1: node 1+b5
      float c2 = a1 * g[2],       c3 = a1 * (1.0f - g[2]);
      P3[0] = c0 * g[3];  P3[1] = c0 * (1.0f - g[3]);        // lev2: node 3+(l>>4)
      P3[2] = c1 * g[4];  P3[3] = c1 * (1.0f - g[4]);
      P3[4] = c2 * g[5];  P3[5] = c2 * (1.0f - g[5]);
      P3[6] = c3 * g[6];  P3[7] = c3 * (1.0f - g[6]);
    }
    unsigned short* prow = P + (long)(b0 + row) * 4096 + (t0 + tr) * 64;
    #pragma unroll
    for (int o = 0; o < 8; ++o) {
      float g3 = g[7 + o];                         // lev3: node 7+o, bit j>>2
      float q0 = P3[o] * g3, q1 = P3[o] * (1.0f - g3);
      float g4a = g[15 + 2 * o], g4b = g[16 + 2 * o];  // lev4: node 15+2o+(j>>2), bit (j>>1)&1
      float r0 = q0 * g4a, r1 = q0 * (1.0f - g4a);
      float r2 = q1 * g4b, r3 = q1 * (1.0f - g4b);
      union { unsigned short u[8]; uint4 v; } ou;
      #pragma unroll
      for (int h = 0; h < 4; ++h) {                // h = j>>1
        float g5 = g[31 + 4 * o + h];              // lev5: node 31+4o+h, bit j&1
        float rr = (h == 0) ? r0 : (h == 1) ? r1 : (h == 2) ? r2 : r3;
        ou.u[2 * h]     = f2bf(rr * g5);
        ou.u[2 * h + 1] = f2bf(rr * (1.0f - g5));
      }
      *(uint4*)(prow + o * 8) = ou.v;
    }
  }
}

// ---------------- GEMM2: out += P(4096x4096) * Wv2^T, 64-row tiles, split-K by 8 ----
__global__ __launch_bounds__(256, 4) void gemm2_k(
    const unsigned short* __restrict__ P,    // [4096][4096] bf16
    const unsigned short* __restrict__ Wv2,  // [128][4096] bf16
    float* __restrict__ out)                 // [4096][128], pre-zeroed
{
  __shared__ unsigned short As[64 * 32];     // 4 KB
  __shared__ unsigned short Bs[128 * 32];    // 8 KB
  const int tid = threadIdx.x;
  const int wave = tid >> 6, lane = tid & 63;
  const int b0 = blockIdx.x * 64;
  const int kc = blockIdx.y;                 // K chunk of 512

  const f32x4 zero = {0.f, 0.f, 0.f, 0.f};
  f32x4 acc[2][4];
  #pragma unroll
  for (int i = 0; i < 2; ++i)
    #pragma unroll
    for (int j = 0; j < 4; ++j) acc[i][j] = zero;

  const int g0 = wave * 64 + lane;           // A granule (256 total: 64 rows x 4 chunks)
  const int g1 = g0 + 256;                   // B granules (512 total)
  const unsigned short* Ag0 = P + (long)(b0 + (g0 >> 2)) * 4096 + kc * 512 + (g0 & 3) * 8;
  const unsigned short* Bg0 = Wv2 + (long)(g0 >> 2) * 4096 + kc * 512 + (g0 & 3) * 8;
  const unsigned short* Bg1 = Wv2 + (long)(g1 >> 2) * 4096 + kc * 512 + (g1 & 3) * 8;
  unsigned short* lA0 = As + (wave * 64) * 8;
  unsigned short* lB0 = Bs + (wave * 64) * 8;
  unsigned short* lB1 = Bs + (wave * 64 + 256) * 8;

  const int wm = (wave >> 1) * 32, wn = (wave & 1) * 64;
  const int mrow = lane & 15, kg = lane >> 4;

  for (int kk = 0; kk < 512; kk += 32) {
    __syncthreads();
    gl_lds16(Ag0 + kk, lA0);
    gl_lds16(Bg0 + kk, lB0);
    gl_lds16(Bg1 + kk, lB1);
    asm volatile("s_waitcnt vmcnt(0)" ::: "memory");
    __syncthreads();

    bf16x8 fa[2], fb[4];
    #pragma unroll
    for (int i = 0; i < 2; ++i)
      fa[i] = *(const bf16x8*)(As + (wm + i * 16 + mrow) * 32 + kg * 8);
    #pragma unroll
    for (int j = 0; j < 4; ++j)
      fb[j] = *(const bf16x8*)(Bs + (wn + j * 16 + mrow) * 32 + kg * 8);
    #pragma unroll
    for (int i = 0; i < 2; ++i)
      #pragma unroll
      for (int j = 0; j < 4; ++j)
        acc[i][j] = __builtin_amdgcn_mfma_f32_16x16x32_bf16(fa[i], fb[j], acc[i][j], 0, 0, 0);
  }

  #pragma unroll
  for (int i = 0; i < 2; ++i)
    #pragma unroll
    for (int j = 0; j < 4; ++j) {
      int col = wn + j * 16 + mrow;
      #pragma unroll
      for (int r = 0; r < 4; ++r) {
        int row = wm + i * 16 + kg * 4 + r;
        atomicAdd(&out[(long)(b0 + row) * 128 + col], acc[i][j][r]);
      }
    }
}

extern "C" void kernel_launch(void* const* d_in, const int* in_sizes, int n_in,
                              void* d_out, int out_size, void* d_ws, size_t ws_size,
                              hipStream_t stream) {
  const float* x     = (const float*)d_in[0];
  const float* W     = (const float*)d_in[1];
  const float* b     = (const float*)d_in[2];
  const float* lw    = (const float*)d_in[3];
  const float* gates = (const float*)d_in[4];
  float* out = (float*)d_out;

  char* ws = (char*)d_ws;
  unsigned short* xb  = (unsigned short*)(ws);                    // 4 MB
  unsigned short* Wt  = (unsigned short*)(ws + (4l  << 20));      // 4 MB
  unsigned short* Wv2 = (unsigned short*)(ws + (8l  << 20));      // 1 MB
  unsigned short* P   = (unsigned short*)(ws + (16l << 20));      // 32 MB

  hipMemsetAsync(out, 0, (size_t)4096 * 128 * sizeof(float), stream);
  hipLaunchKernelGGL(prep_all_k,   dim3(2432),   dim3(256), 0, stream,
                     x, W, gates, lw, xb, Wt, Wv2);
  hipLaunchKernelGGL(gemm1_tree_k, dim3(32, 32), dim3(256), 0, stream, xb, Wt, b, P);
  hipLaunchKernelGGL(gemm2_k,      dim3(64, 8),  dim3(256), 0, stream, P, Wv2, out);
}